// Round 10
// baseline (373.373 us; speedup 1.0000x reference)
//
#include <hip/hip_runtime.h>
#include <hip/hip_bf16.h>
#include <stdint.h>

typedef __bf16 bf16x8 __attribute__((ext_vector_type(8)));
typedef float f32x4 __attribute__((ext_vector_type(4)));
typedef unsigned short u16x8 __attribute__((ext_vector_type(8)));

#define AS1 __attribute__((address_space(1)))
#define AS3 __attribute__((address_space(3)))

__constant__ float c_nf4[16] = {
    -1.0f, -0.6961928009986877f, -0.5250730514526367f, -0.39491748809814453f,
    -0.28444138169288635f, -0.18477343022823334f, -0.09105003625154495f, 0.0f,
    0.07958029955625534f, 0.16093020141124725f, 0.24611230194568634f,
    0.33791524171829224f, 0.44070982933044434f, 0.5626170039176941f,
    0.7229568362236023f, 1.0f};

__device__ __forceinline__ unsigned short f2bf_rne(float f) {
  unsigned int u = __builtin_bit_cast(unsigned int, f);
  u += 0x7FFFu + ((u >> 16) & 1u);
  return (unsigned short)(u >> 16);
}

// Fused prep: chunks [0, w8) dequant+LoRA-fold W; chunks [w8, w8+x8) cvt x.
__global__ __launch_bounds__(256) void k_prep(
    const int* __restrict__ q, const float* __restrict__ scale,
    const float* __restrict__ lA, const float* __restrict__ lB,
    const float* __restrict__ x, unsigned short* __restrict__ w,
    unsigned short* __restrict__ xb, int IN, int shIN, int R,
    long w8, long x8) {
  long idx = (long)blockIdx.x * 256 + threadIdx.x;
  if (idx < w8) {
    long e0 = idx * 8;
    int o = (int)(e0 >> shIN);
    int i0 = (int)(e0 & (IN - 1));
    float s = scale[e0 >> 6];
    const int* qp = q + e0;
    int4 qa = *(const int4*)qp;
    int4 qb = *(const int4*)(qp + 4);
    float v[8];
    v[0] = c_nf4[qa.x & 15] * s; v[1] = c_nf4[qa.y & 15] * s;
    v[2] = c_nf4[qa.z & 15] * s; v[3] = c_nf4[qa.w & 15] * s;
    v[4] = c_nf4[qb.x & 15] * s; v[5] = c_nf4[qb.y & 15] * s;
    v[6] = c_nf4[qb.z & 15] * s; v[7] = c_nf4[qb.w & 15] * s;
    for (int r = 0; r < R; ++r) {
      float br = 4.0f * lB[o * R + r];
      const float* ap = lA + (long)r * IN + i0;
      float4 a0 = *(const float4*)ap;
      float4 a1 = *(const float4*)(ap + 4);
      v[0] += br * a0.x; v[1] += br * a0.y; v[2] += br * a0.z; v[3] += br * a0.w;
      v[4] += br * a1.x; v[5] += br * a1.y; v[6] += br * a1.z; v[7] += br * a1.w;
    }
    u16x8 pk;
#pragma unroll
    for (int j = 0; j < 8; ++j) pk[j] = f2bf_rne(v[j]);
    *(u16x8*)(w + e0) = pk;
  } else {
    long i2 = idx - w8;
    if (i2 >= x8) return;
    long e0 = i2 * 8;
    float4 a0 = *(const float4*)(x + e0);
    float4 a1 = *(const float4*)(x + e0 + 4);
    u16x8 pk;
    pk[0] = f2bf_rne(a0.x); pk[1] = f2bf_rne(a0.y);
    pk[2] = f2bf_rne(a0.z); pk[3] = f2bf_rne(a0.w);
    pk[4] = f2bf_rne(a1.x); pk[5] = f2bf_rne(a1.y);
    pk[6] = f2bf_rne(a1.z); pk[7] = f2bf_rne(a1.w);
    *(u16x8*)(xb + e0) = pk;
  }
}

// ---------------------------------------------------------------------------
// 256x256 tile, BK=64, 8 waves (2M x 4N). R10: ONE barrier + ONE vmcnt(0)
// per K-tile. Staging leads by exactly 1 tile into buf^1 (dead after the
// tile-start barrier), so no per-phase barriers are needed; waves free-run
// within the tile and the compiler schedules counted lgkm waits per MFMA
// quadrant. vmcnt(0) at tile end is satisfied-by-construction (stages were
// issued a full tile (~2400cy) earlier).
// ---------------------------------------------------------------------------
__global__ __launch_bounds__(512, 2) void k_gemm_256(
    const unsigned short* __restrict__ Xb, const unsigned short* __restrict__ Wb,
    const float* __restrict__ bias, float* __restrict__ out,
    int M, int N, int K) {
  __shared__ char smem[131072];
  const int tid = threadIdx.x;
  const int wid = tid >> 6;
  const int lane = tid & 63;
  const int wr = wid >> 2;
  const int wc = wid & 3;
  const int wcl = wc & 1;
  const int l15 = lane & 15;
  const int l16 = lane >> 4;

  // reader swizzle decomposition: (kk*64 + l16*16) ^ ((l15&7)<<4)
  const int kflip = (l15 & 4) ? 64 : 0;
  const int lowx = ((l16 ^ (l15 & 3)) << 4);
  const int baseA0 = wr * 16384 + l15 * 128 + lowx + kflip;
  const int baseA1 = wr * 16384 + l15 * 128 + lowx + (64 ^ kflip);
  const int baseB0 = 65536 + (wc >> 1) * 16384 + wcl * 8192 + l15 * 128 + lowx + kflip;
  const int baseB1 = baseB0 + (64 ^ kflip) - kflip;

  int bid = blockIdx.x;
  const int nwg = gridDim.x;
  if ((nwg & 7) == 0) { const int cpx = nwg >> 3; bid = (bid & 7) * cpx + (bid >> 3); }
  const int nbn = N >> 8;
  const int m0 = (bid / nbn) << 8;
  const int n0 = (bid % nbn) << 8;

  // per-lane pre-swizzled global source offsets for staging
  int rowj[2], gcj[2];
#pragma unroll
  for (int j = 0; j < 2; ++j) {
    const int lo = wid * 2048 + j * 1024 + lane * 16;
    const int row = lo >> 7;
    const int ls = lo ^ ((row & 7) << 4);
    rowj[j] = row;
    gcj[j] = (ls & 127) >> 1;
  }
  const size_t halfstep = (size_t)128 * K;
  const unsigned short* pSA0[2]; const unsigned short* pSA1[2];
  const unsigned short* pSB0[2]; const unsigned short* pSB1[2];
#pragma unroll
  for (int j = 0; j < 2; ++j) {
    pSA0[j] = Xb + (size_t)(m0 + rowj[j]) * K + gcj[j];
    pSA1[j] = pSA0[j] + halfstep;
    pSB0[j] = Wb + (size_t)(n0 + rowj[j]) * K + gcj[j];
    pSB1[j] = pSB0[j] + halfstep;
  }

#define ST_A(bufl, h, coff)                                                          \
  {                                                                                  \
    __builtin_amdgcn_global_load_lds((const AS1 void*)(pSA##h[0] + (coff)),          \
        (AS3 void*)(smem + (bufl) * 32768 + (h) * 16384 + wid * 2048), 16, 0, 0);    \
    __builtin_amdgcn_global_load_lds((const AS1 void*)(pSA##h[1] + (coff)),          \
        (AS3 void*)(smem + (bufl) * 32768 + (h) * 16384 + wid * 2048 + 1024),        \
        16, 0, 0);                                                                   \
  }
#define ST_B(bufl, h, coff)                                                          \
  {                                                                                  \
    __builtin_amdgcn_global_load_lds((const AS1 void*)(pSB##h[0] + (coff)),          \
        (AS3 void*)(smem + 65536 + (bufl) * 32768 + (h) * 16384 + wid * 2048),       \
        16, 0, 0);                                                                   \
    __builtin_amdgcn_global_load_lds((const AS1 void*)(pSB##h[1] + (coff)),          \
        (AS3 void*)(smem + 65536 + (bufl) * 32768 + (h) * 16384 + wid * 2048 + 1024),\
        16, 0, 0);                                                                   \
  }

  bf16x8 afA[4][2], afB[4][2], b0[2][2], b1[2][2];
  f32x4 acc[8][4];
#pragma unroll
  for (int i = 0; i < 8; ++i)
#pragma unroll
    for (int j = 0; j < 4; ++j) acc[i][j] = (f32x4)0.0f;

#define RD_A(bufl, mq, dst)                                                          \
  _Pragma("unroll") for (int ii = 0; ii < 4; ++ii) {                                 \
    dst[ii][0] = *(const bf16x8*)(smem + baseA0 +                                    \
                                  ((bufl) * 32768 + (mq) * 8192 + ii * 2048));       \
    dst[ii][1] = *(const bf16x8*)(smem + baseA1 +                                    \
                                  ((bufl) * 32768 + (mq) * 8192 + ii * 2048));       \
  }
#define RD_B(bufl, q, arr)                                                           \
  _Pragma("unroll") for (int jj = 0; jj < 2; ++jj) {                                 \
    arr[jj][0] = *(const bf16x8*)(smem + baseB0 +                                    \
                                  ((bufl) * 32768 + (q) * 4096 + jj * 2048));        \
    arr[jj][1] = *(const bf16x8*)(smem + baseB1 +                                    \
                                  ((bufl) * 32768 + (q) * 4096 + jj * 2048));        \
  }
#define MFMA_Q(mq, q, A, arr)                                                        \
  _Pragma("unroll") for (int kk = 0; kk < 2; ++kk)                                   \
  _Pragma("unroll") for (int ii = 0; ii < 4; ++ii)                                   \
  _Pragma("unroll") for (int jj = 0; jj < 2; ++jj)                                   \
      acc[(mq)*4+ii][(q)*2+jj] = __builtin_amdgcn_mfma_f32_16x16x32_bf16(            \
          A[ii][kk], arr[jj][kk], acc[(mq)*4+ii][(q)*2+jj], 0, 0, 0);

#define BAR __builtin_amdgcn_s_barrier()
#define PRIO1 __builtin_amdgcn_s_setprio(1)
#define PRIO0 __builtin_amdgcn_s_setprio(0)
#define VM0 asm volatile("s_waitcnt vmcnt(0)" ::: "memory")

  // One-barrier tile: reads -> stages(t+1 -> buf^1) -> MFMAs -> vm-drain -> BAR
#define TILE(bufl, SCN)                                                              \
  RD_A(bufl, 0, afA)                                                                 \
  RD_B(bufl, 0, b0)                                                                  \
  RD_B(bufl, 1, b1)                                                                  \
  RD_A(bufl, 1, afB)                                                                 \
  ST_A((bufl) ^ 1, 0, SCN) ST_A((bufl) ^ 1, 1, SCN)                                  \
  ST_B((bufl) ^ 1, 0, SCN) ST_B((bufl) ^ 1, 1, SCN)                                  \
  PRIO1; MFMA_Q(0, 0, afA, b0) PRIO0;                                                \
  PRIO1; MFMA_Q(0, 1, afA, b1) PRIO0;                                                \
  PRIO1; MFMA_Q(1, 0, afB, b0) PRIO0;                                                \
  PRIO1; MFMA_Q(1, 1, afB, b1) PRIO0;                                                \
  VM0;                                                                               \
  BAR;

  const int NT = K >> 6;

  // prologue: stage tile0 -> buf0; drain; barrier.
  ST_A(0, 0, 0) ST_A(0, 1, 0) ST_B(0, 0, 0) ST_B(0, 1, 0)
  VM0;
  BAR;

  for (int t = 0; t < NT; t += 2) {
    // TILE(0): stages tile t+1 at col +64. TILE(1): stages t+2 at +128
    // (wrapped to col 0 dummy on the last pair to avoid OOB).
    const int sc2 = (t + 2 < NT) ? 128 : 128 - K;
    TILE(0, 64)
    TILE(1, sc2)
#pragma unroll
    for (int j = 0; j < 2; ++j) { pSA0[j] += 128; pSA1[j] += 128; pSB0[j] += 128; pSB1[j] += 128; }
  }

  // epilogue: C/D layout col=lane&15, row=(lane>>4)*4+j
#pragma unroll
  for (int nf = 0; nf < 4; ++nf) {
    const int col = n0 + wc * 64 + nf * 16 + l15;
    const float bv = bias[col];
#pragma unroll
    for (int mi = 0; mi < 8; ++mi) {
      const int row = m0 + wr * 128 + mi * 16 + l16 * 4;
#pragma unroll
      for (int j = 0; j < 4; ++j)
        out[(size_t)(row + j) * N + col] = acc[mi][nf][j] + bv;
    }
  }
#undef ST_A
#undef ST_B
#undef RD_A
#undef RD_B
#undef MFMA_Q
#undef BAR
#undef PRIO1
#undef PRIO0
#undef VM0
#undef TILE
}

extern "C" void kernel_launch(void* const* d_in, const int* in_sizes, int n_in,
                              void* d_out, int out_size, void* d_ws, size_t ws_size,
                              hipStream_t stream) {
  const float* x = (const float*)d_in[0];
  const int* qw = (const int*)d_in[1];
  const float* qs = (const float*)d_in[2];
  const float* bias = (const float*)d_in[3];
  const float* lA = (const float*)d_in[4];
  const float* lB = (const float*)d_in[5];
  float* out = (float*)d_out;

  const int OUT = in_sizes[3];
  const long qn = (long)in_sizes[1];
  const int IN = (int)(qn / OUT);
  const int R = in_sizes[5] / OUT;
  const long xn = (long)in_sizes[0];
  const int M = (int)(xn / IN);
  const int N = OUT, K = IN;

  unsigned short* Wb = (unsigned short*)d_ws;   // OUT*IN bf16
  unsigned short* Xb = Wb + qn;                 // M*IN bf16

  const int shIN = 31 - __builtin_clz((unsigned)IN);

  const long w8 = qn / 8;
  const long x8 = xn / 8;
  const long nchunks = w8 + x8;
  k_prep<<<(int)((nchunks + 255) / 256), 256, 0, stream>>>(
      qw, qs, lA, lB, x, Wb, Xb, IN, shIN, R, w8, x8);

  dim3 grid((M / 256) * (N / 256));
  k_gemm_256<<<grid, 512, 0, stream>>>(Xb, Wb, bias, out, M, N, K);
}

// Round 11
// 295.438 us; speedup vs baseline: 1.2638x; 1.2638x over previous
//
#include <hip/hip_runtime.h>
#include <hip/hip_bf16.h>
#include <stdint.h>

typedef __bf16 bf16x8 __attribute__((ext_vector_type(8)));
typedef float f32x4 __attribute__((ext_vector_type(4)));
typedef unsigned short u16x8 __attribute__((ext_vector_type(8)));

#define AS1 __attribute__((address_space(1)))
#define AS3 __attribute__((address_space(3)))

__constant__ float c_nf4[16] = {
    -1.0f, -0.6961928009986877f, -0.5250730514526367f, -0.39491748809814453f,
    -0.28444138169288635f, -0.18477343022823334f, -0.09105003625154495f, 0.0f,
    0.07958029955625534f, 0.16093020141124725f, 0.24611230194568634f,
    0.33791524171829224f, 0.44070982933044434f, 0.5626170039176941f,
    0.7229568362236023f, 1.0f};

__device__ __forceinline__ unsigned short f2bf_rne(float f) {
  unsigned int u = __builtin_bit_cast(unsigned int, f);
  u += 0x7FFFu + ((u >> 16) & 1u);
  return (unsigned short)(u >> 16);
}

// Fused prep: chunks [0, w8) dequant+LoRA-fold W; chunks [w8, w8+x8) cvt x.
__global__ __launch_bounds__(256) void k_prep(
    const int* __restrict__ q, const float* __restrict__ scale,
    const float* __restrict__ lA, const float* __restrict__ lB,
    const float* __restrict__ x, unsigned short* __restrict__ w,
    unsigned short* __restrict__ xb, int IN, int shIN, int R,
    long w8, long x8) {
  long idx = (long)blockIdx.x * 256 + threadIdx.x;
  if (idx < w8) {
    long e0 = idx * 8;
    int o = (int)(e0 >> shIN);
    int i0 = (int)(e0 & (IN - 1));
    float s = scale[e0 >> 6];
    const int* qp = q + e0;
    int4 qa = *(const int4*)qp;
    int4 qb = *(const int4*)(qp + 4);
    float v[8];
    v[0] = c_nf4[qa.x & 15] * s; v[1] = c_nf4[qa.y & 15] * s;
    v[2] = c_nf4[qa.z & 15] * s; v[3] = c_nf4[qa.w & 15] * s;
    v[4] = c_nf4[qb.x & 15] * s; v[5] = c_nf4[qb.y & 15] * s;
    v[6] = c_nf4[qb.z & 15] * s; v[7] = c_nf4[qb.w & 15] * s;
    for (int r = 0; r < R; ++r) {
      float br = 4.0f * lB[o * R + r];
      const float* ap = lA + (long)r * IN + i0;
      float4 a0 = *(const float4*)ap;
      float4 a1 = *(const float4*)(ap + 4);
      v[0] += br * a0.x; v[1] += br * a0.y; v[2] += br * a0.z; v[3] += br * a0.w;
      v[4] += br * a1.x; v[5] += br * a1.y; v[6] += br * a1.z; v[7] += br * a1.w;
    }
    u16x8 pk;
#pragma unroll
    for (int j = 0; j < 8; ++j) pk[j] = f2bf_rne(v[j]);
    *(u16x8*)(w + e0) = pk;
  } else {
    long i2 = idx - w8;
    if (i2 >= x8) return;
    long e0 = i2 * 8;
    float4 a0 = *(const float4*)(x + e0);
    float4 a1 = *(const float4*)(x + e0 + 4);
    u16x8 pk;
    pk[0] = f2bf_rne(a0.x); pk[1] = f2bf_rne(a0.y);
    pk[2] = f2bf_rne(a0.z); pk[3] = f2bf_rne(a0.w);
    pk[4] = f2bf_rne(a1.x); pk[5] = f2bf_rne(a1.y);
    pk[6] = f2bf_rne(a1.z); pk[7] = f2bf_rne(a1.w);
    *(u16x8*)(xb + e0) = pk;
  }
}

// ---------------------------------------------------------------------------
// 256x256 tile, BK=64, 8 waves (2M x 4N). R11 = R6 with wait restructuring:
// 3 barriers/tile (p1,p2,p3), single counted vmcnt(8) at p3 (drains stages
// at 4-5 phase lead, satisfied-by-construction), each tile reads its own
// afA/b0 at p0 (safe: p3's VM8+BAR published all waves' t+1 stages).
//  p0: rd afA,b0; LGK0; MFMA(0,0); rd b1
//  p1: LGK0; MFMA(0,1); rd afB; BAR
//  p2: LGK0; MFMA(1,0); stage B(t+2)->buf; BAR
//  p3: MFMA(1,1); stage A(t+2)->buf; VM8; BAR
// Cross-wave LDS discipline: every read of staged data follows a
// [per-wave vm-drain -> barrier] pair; every stage follows a barrier after
// the region's last reads completed (per-wave lgkm0 before that barrier).
// ---------------------------------------------------------------------------
__global__ __launch_bounds__(512, 2) void k_gemm_256(
    const unsigned short* __restrict__ Xb, const unsigned short* __restrict__ Wb,
    const float* __restrict__ bias, float* __restrict__ out,
    int M, int N, int K) {
  __shared__ char smem[131072];
  const int tid = threadIdx.x;
  const int wid = tid >> 6;
  const int lane = tid & 63;
  const int wr = wid >> 2;
  const int wc = wid & 3;
  const int wcl = wc & 1;
  const int l15 = lane & 15;
  const int l16 = lane >> 4;

  // reader swizzle decomposition: (kk*64 + l16*16) ^ ((l15&7)<<4)
  const int kflip = (l15 & 4) ? 64 : 0;
  const int lowx = ((l16 ^ (l15 & 3)) << 4);
  const int baseA0 = wr * 16384 + l15 * 128 + lowx + kflip;
  const int baseA1 = wr * 16384 + l15 * 128 + lowx + (64 ^ kflip);
  const int baseB0 = 65536 + (wc >> 1) * 16384 + wcl * 8192 + l15 * 128 + lowx + kflip;
  const int baseB1 = baseB0 + (64 ^ kflip) - kflip;

  int bid = blockIdx.x;
  const int nwg = gridDim.x;
  if ((nwg & 7) == 0) { const int cpx = nwg >> 3; bid = (bid & 7) * cpx + (bid >> 3); }
  const int nbn = N >> 8;
  const int m0 = (bid / nbn) << 8;
  const int n0 = (bid % nbn) << 8;

  // per-lane pre-swizzled global source offsets for staging
  int rowj[2], gcj[2];
#pragma unroll
  for (int j = 0; j < 2; ++j) {
    const int lo = wid * 2048 + j * 1024 + lane * 16;
    const int row = lo >> 7;
    const int ls = lo ^ ((row & 7) << 4);
    rowj[j] = row;
    gcj[j] = (ls & 127) >> 1;
  }
  const size_t halfstep = (size_t)128 * K;
  const unsigned short* pSA0[2]; const unsigned short* pSA1[2];
  const unsigned short* pSB0[2]; const unsigned short* pSB1[2];
#pragma unroll
  for (int j = 0; j < 2; ++j) {
    pSA0[j] = Xb + (size_t)(m0 + rowj[j]) * K + gcj[j];
    pSA1[j] = pSA0[j] + halfstep;
    pSB0[j] = Wb + (size_t)(n0 + rowj[j]) * K + gcj[j];
    pSB1[j] = pSB0[j] + halfstep;
  }

#define ST_A(bufl, h, coff)                                                          \
  {                                                                                  \
    __builtin_amdgcn_global_load_lds((const AS1 void*)(pSA##h[0] + (coff)),          \
        (AS3 void*)(smem + (bufl) * 32768 + (h) * 16384 + wid * 2048), 16, 0, 0);    \
    __builtin_amdgcn_global_load_lds((const AS1 void*)(pSA##h[1] + (coff)),          \
        (AS3 void*)(smem + (bufl) * 32768 + (h) * 16384 + wid * 2048 + 1024),        \
        16, 0, 0);                                                                   \
  }
#define ST_B(bufl, h, coff)                                                          \
  {                                                                                  \
    __builtin_amdgcn_global_load_lds((const AS1 void*)(pSB##h[0] + (coff)),          \
        (AS3 void*)(smem + 65536 + (bufl) * 32768 + (h) * 16384 + wid * 2048),       \
        16, 0, 0);                                                                   \
    __builtin_amdgcn_global_load_lds((const AS1 void*)(pSB##h[1] + (coff)),          \
        (AS3 void*)(smem + 65536 + (bufl) * 32768 + (h) * 16384 + wid * 2048 + 1024),\
        16, 0, 0);                                                                   \
  }

  bf16x8 afA[4][2], afB[4][2], b0[2][2], b1[2][2];
  f32x4 acc[8][4];
#pragma unroll
  for (int i = 0; i < 8; ++i)
#pragma unroll
    for (int j = 0; j < 4; ++j) acc[i][j] = (f32x4)0.0f;

#define RD_A(bufl, mq, dst)                                                          \
  _Pragma("unroll") for (int ii = 0; ii < 4; ++ii) {                                 \
    dst[ii][0] = *(const bf16x8*)(smem + baseA0 +                                    \
                                  ((bufl) * 32768 + (mq) * 8192 + ii * 2048));       \
    dst[ii][1] = *(const bf16x8*)(smem + baseA1 +                                    \
                                  ((bufl) * 32768 + (mq) * 8192 + ii * 2048));       \
  }
#define RD_B(bufl, q, arr)                                                           \
  _Pragma("unroll") for (int jj = 0; jj < 2; ++jj) {                                 \
    arr[jj][0] = *(const bf16x8*)(smem + baseB0 +                                    \
                                  ((bufl) * 32768 + (q) * 4096 + jj * 2048));        \
    arr[jj][1] = *(const bf16x8*)(smem + baseB1 +                                    \
                                  ((bufl) * 32768 + (q) * 4096 + jj * 2048));        \
  }
#define MFMA_Q(mq, q, A, arr)                                                        \
  _Pragma("unroll") for (int kk = 0; kk < 2; ++kk)                                   \
  _Pragma("unroll") for (int ii = 0; ii < 4; ++ii)                                   \
  _Pragma("unroll") for (int jj = 0; jj < 2; ++jj)                                   \
      acc[(mq)*4+ii][(q)*2+jj] = __builtin_amdgcn_mfma_f32_16x16x32_bf16(            \
          A[ii][kk], arr[jj][kk], acc[(mq)*4+ii][(q)*2+jj], 0, 0, 0);

#define BAR __builtin_amdgcn_s_barrier()
#define PRIO1 __builtin_amdgcn_s_setprio(1)
#define PRIO0 __builtin_amdgcn_s_setprio(0)
#define LGK0                                               \
  {                                                        \
    asm volatile("s_waitcnt lgkmcnt(0)" ::: "memory");     \
    __builtin_amdgcn_sched_barrier(0);                     \
  }
#define VM8                                                \
  {                                                        \
    asm volatile("s_waitcnt vmcnt(8)" ::: "memory");       \
    __builtin_amdgcn_sched_barrier(0);                     \
  }
#define VM8P asm volatile("s_waitcnt vmcnt(8)" ::: "memory")

#define SUBTILE(bufl, SC)                                                            \
  /* p0: read own afA,b0 (published by prev p3 VM8+BAR); MFMA; read b1 */            \
  RD_A(bufl, 0, afA)                                                                 \
  RD_B(bufl, 0, b0)                                                                  \
  LGK0;                                                                              \
  PRIO1; MFMA_Q(0, 0, afA, b0) PRIO0;                                                \
  RD_B(bufl, 1, b1)                                                                  \
  /* p1 */                                                                           \
  LGK0;                                                                              \
  PRIO1; MFMA_Q(0, 1, afA, b1) PRIO0;                                                \
  RD_A(bufl, 1, afB)                                                                 \
  BAR;                                                                               \
  /* p2: b0/b1 reads of buf complete in all waves (p1 BAR) -> stage B(t+2) */        \
  LGK0;                                                                              \
  PRIO1; MFMA_Q(1, 0, afB, b0) PRIO0;                                                \
  ST_B(bufl, 0, SC) ST_B(bufl, 1, SC)                                                \
  BAR;                                                                               \
  /* p3: afA/afB reads complete (p2 BAR) -> stage A(t+2); drain t+1 stages */        \
  PRIO1; MFMA_Q(1, 1, afB, b1) PRIO0;                                                \
  ST_A(bufl, 0, SC) ST_A(bufl, 1, SC)                                                \
  VM8;                                                                               \
  BAR;

  const int NT = K >> 6;

  // prologue: stage tile0->buf0, tile1->buf1 (queue order [A0,B0,B1,A1]);
  // VM8 drains tile0's 8, leaves [B1,A1] = steady-state pattern; BAR.
  ST_A(0, 0, 0) ST_A(0, 1, 0) ST_B(0, 0, 0) ST_B(0, 1, 0)
  ST_B(1, 0, 64) ST_B(1, 1, 64) ST_A(1, 0, 64) ST_A(1, 1, 64)
  VM8P;
  BAR;
#pragma unroll
  for (int j = 0; j < 2; ++j) { pSA0[j] += 128; pSA1[j] += 128; pSB0[j] += 128; pSB1[j] += 128; }

  for (int t = 0; t < NT; t += 2) {
    SUBTILE(0, 0)
    SUBTILE(1, 64)
    if (t + 4 < NT) {
#pragma unroll
      for (int j = 0; j < 2; ++j) { pSA0[j] += 128; pSA1[j] += 128; pSB0[j] += 128; pSB1[j] += 128; }
    }
  }

  // epilogue: C/D layout col=lane&15, row=(lane>>4)*4+j
#pragma unroll
  for (int nf = 0; nf < 4; ++nf) {
    const int col = n0 + wc * 64 + nf * 16 + l15;
    const float bv = bias[col];
#pragma unroll
    for (int mi = 0; mi < 8; ++mi) {
      const int row = m0 + wr * 128 + mi * 16 + l16 * 4;
#pragma unroll
      for (int j = 0; j < 4; ++j)
        out[(size_t)(row + j) * N + col] = acc[mi][nf][j] + bv;
    }
  }
#undef ST_A
#undef ST_B
#undef RD_A
#undef RD_B
#undef MFMA_Q
#undef BAR
#undef PRIO1
#undef PRIO0
#undef LGK0
#undef VM8
#undef VM8P
#undef SUBTILE
}

extern "C" void kernel_launch(void* const* d_in, const int* in_sizes, int n_in,
                              void* d_out, int out_size, void* d_ws, size_t ws_size,
                              hipStream_t stream) {
  const float* x = (const float*)d_in[0];
  const int* qw = (const int*)d_in[1];
  const float* qs = (const float*)d_in[2];
  const float* bias = (const float*)d_in[3];
  const float* lA = (const float*)d_in[4];
  const float* lB = (const float*)d_in[5];
  float* out = (float*)d_out;

  const int OUT = in_sizes[3];
  const long qn = (long)in_sizes[1];
  const int IN = (int)(qn / OUT);
  const int R = in_sizes[5] / OUT;
  const long xn = (long)in_sizes[0];
  const int M = (int)(xn / IN);
  const int N = OUT, K = IN;

  unsigned short* Wb = (unsigned short*)d_ws;   // OUT*IN bf16
  unsigned short* Xb = Wb + qn;                 // M*IN bf16

  const int shIN = 31 - __builtin_clz((unsigned)IN);

  const long w8 = qn / 8;
  const long x8 = xn / 8;
  const long nchunks = w8 + x8;
  k_prep<<<(int)((nchunks + 255) / 256), 256, 0, stream>>>(
      qw, qs, lA, lB, x, Wb, Xb, IN, shIN, R, w8, x8);

  dim3 grid((M / 256) * (N / 256));
  k_gemm_256<<<grid, 512, 0, stream>>>(Xb, Wb, bias, out, M, N, K);
}

// Round 12
// 292.605 us; speedup vs baseline: 1.2760x; 1.0097x over previous
//
#include <hip/hip_runtime.h>
#include <hip/hip_bf16.h>
#include <stdint.h>

typedef __bf16 bf16x8 __attribute__((ext_vector_type(8)));
typedef float f32x4 __attribute__((ext_vector_type(4)));
typedef unsigned short u16x8 __attribute__((ext_vector_type(8)));

#define AS1 __attribute__((address_space(1)))
#define AS3 __attribute__((address_space(3)))

__constant__ float c_nf4[16] = {
    -1.0f, -0.6961928009986877f, -0.5250730514526367f, -0.39491748809814453f,
    -0.28444138169288635f, -0.18477343022823334f, -0.09105003625154495f, 0.0f,
    0.07958029955625534f, 0.16093020141124725f, 0.24611230194568634f,
    0.33791524171829224f, 0.44070982933044434f, 0.5626170039176941f,
    0.7229568362236023f, 1.0f};

__device__ __forceinline__ unsigned short f2bf_rne(float f) {
  unsigned int u = __builtin_bit_cast(unsigned int, f);
  u += 0x7FFFu + ((u >> 16) & 1u);
  return (unsigned short)(u >> 16);
}

// Fused prep: chunks [0, w8) dequant+LoRA-fold W; chunks [w8, w8+x8) cvt x.
__global__ __launch_bounds__(256) void k_prep(
    const int* __restrict__ q, const float* __restrict__ scale,
    const float* __restrict__ lA, const float* __restrict__ lB,
    const float* __restrict__ x, unsigned short* __restrict__ w,
    unsigned short* __restrict__ xb, int IN, int shIN, int R,
    long w8, long x8) {
  long idx = (long)blockIdx.x * 256 + threadIdx.x;
  if (idx < w8) {
    long e0 = idx * 8;
    int o = (int)(e0 >> shIN);
    int i0 = (int)(e0 & (IN - 1));
    float s = scale[e0 >> 6];
    const int* qp = q + e0;
    int4 qa = *(const int4*)qp;
    int4 qb = *(const int4*)(qp + 4);
    float v[8];
    v[0] = c_nf4[qa.x & 15] * s; v[1] = c_nf4[qa.y & 15] * s;
    v[2] = c_nf4[qa.z & 15] * s; v[3] = c_nf4[qa.w & 15] * s;
    v[4] = c_nf4[qb.x & 15] * s; v[5] = c_nf4[qb.y & 15] * s;
    v[6] = c_nf4[qb.z & 15] * s; v[7] = c_nf4[qb.w & 15] * s;
    for (int r = 0; r < R; ++r) {
      float br = 4.0f * lB[o * R + r];
      const float* ap = lA + (long)r * IN + i0;
      float4 a0 = *(const float4*)ap;
      float4 a1 = *(const float4*)(ap + 4);
      v[0] += br * a0.x; v[1] += br * a0.y; v[2] += br * a0.z; v[3] += br * a0.w;
      v[4] += br * a1.x; v[5] += br * a1.y; v[6] += br * a1.z; v[7] += br * a1.w;
    }
    u16x8 pk;
#pragma unroll
    for (int j = 0; j < 8; ++j) pk[j] = f2bf_rne(v[j]);
    *(u16x8*)(w + e0) = pk;
  } else {
    long i2 = idx - w8;
    if (i2 >= x8) return;
    long e0 = i2 * 8;
    float4 a0 = *(const float4*)(x + e0);
    float4 a1 = *(const float4*)(x + e0 + 4);
    u16x8 pk;
    pk[0] = f2bf_rne(a0.x); pk[1] = f2bf_rne(a0.y);
    pk[2] = f2bf_rne(a0.z); pk[3] = f2bf_rne(a0.w);
    pk[4] = f2bf_rne(a1.x); pk[5] = f2bf_rne(a1.y);
    pk[6] = f2bf_rne(a1.z); pk[7] = f2bf_rne(a1.w);
    *(u16x8*)(xb + e0) = pk;
  }
}

// ---------------------------------------------------------------------------
// 256x256 tile, BK=64, 8 waves (2M x 4N), 4 phases/tile (T2+T3+T4+T5).
// R6 reads-early schedule (verified best: 226us GEMM, MfmaUtil 55.4%, 0 bank
// conflicts): each phase = [lgkm-wait; MFMA; NEXT-phase reads/stages; BAR] so
// ds_read issue+latency overlaps barrier convergence and the co-resident
// wave's MFMA. Race discipline: a region's stage issues >=1 barrier after
// that region's reads completed (lgkm0 precedes the phase's trailing BAR);
// VM4 before p2's BAR so p3's next-buf pre-reads follow an all-wave drain.
// ---------------------------------------------------------------------------
__global__ __launch_bounds__(512, 2) void k_gemm_256(
    const unsigned short* __restrict__ Xb, const unsigned short* __restrict__ Wb,
    const float* __restrict__ bias, float* __restrict__ out,
    int M, int N, int K) {
  __shared__ char smem[131072];
  const int tid = threadIdx.x;
  const int wid = tid >> 6;
  const int lane = tid & 63;
  const int wr = wid >> 2;
  const int wc = wid & 3;
  const int wcl = wc & 1;
  const int l15 = lane & 15;
  const int l16 = lane >> 4;

  // reader swizzle decomposition: (kk*64 + l16*16) ^ ((l15&7)<<4)
  const int kflip = (l15 & 4) ? 64 : 0;
  const int lowx = ((l16 ^ (l15 & 3)) << 4);
  const int baseA0 = wr * 16384 + l15 * 128 + lowx + kflip;
  const int baseA1 = wr * 16384 + l15 * 128 + lowx + (64 ^ kflip);
  const int baseB0 = 65536 + (wc >> 1) * 16384 + wcl * 8192 + l15 * 128 + lowx + kflip;
  const int baseB1 = baseB0 + (64 ^ kflip) - kflip;

  int bid = blockIdx.x;
  const int nwg = gridDim.x;
  if ((nwg & 7) == 0) { const int cpx = nwg >> 3; bid = (bid & 7) * cpx + (bid >> 3); }
  const int nbn = N >> 8;
  const int m0 = (bid / nbn) << 8;
  const int n0 = (bid % nbn) << 8;

  // per-lane pre-swizzled global source offsets for staging
  int rowj[2], gcj[2];
#pragma unroll
  for (int j = 0; j < 2; ++j) {
    const int lo = wid * 2048 + j * 1024 + lane * 16;
    const int row = lo >> 7;
    const int ls = lo ^ ((row & 7) << 4);
    rowj[j] = row;
    gcj[j] = (ls & 127) >> 1;
  }
  const size_t halfstep = (size_t)128 * K;
  const unsigned short* pSA0[2]; const unsigned short* pSA1[2];
  const unsigned short* pSB0[2]; const unsigned short* pSB1[2];
#pragma unroll
  for (int j = 0; j < 2; ++j) {
    pSA0[j] = Xb + (size_t)(m0 + rowj[j]) * K + gcj[j];
    pSA1[j] = pSA0[j] + halfstep;
    pSB0[j] = Wb + (size_t)(n0 + rowj[j]) * K + gcj[j];
    pSB1[j] = pSB0[j] + halfstep;
  }

#define ST_A(bufl, h, coff)                                                          \
  {                                                                                  \
    __builtin_amdgcn_global_load_lds((const AS1 void*)(pSA##h[0] + (coff)),          \
        (AS3 void*)(smem + (bufl) * 32768 + (h) * 16384 + wid * 2048), 16, 0, 0);    \
    __builtin_amdgcn_global_load_lds((const AS1 void*)(pSA##h[1] + (coff)),          \
        (AS3 void*)(smem + (bufl) * 32768 + (h) * 16384 + wid * 2048 + 1024),        \
        16, 0, 0);                                                                   \
  }
#define ST_B(bufl, h, coff)                                                          \
  {                                                                                  \
    __builtin_amdgcn_global_load_lds((const AS1 void*)(pSB##h[0] + (coff)),          \
        (AS3 void*)(smem + 65536 + (bufl) * 32768 + (h) * 16384 + wid * 2048),       \
        16, 0, 0);                                                                   \
    __builtin_amdgcn_global_load_lds((const AS1 void*)(pSB##h[1] + (coff)),          \
        (AS3 void*)(smem + 65536 + (bufl) * 32768 + (h) * 16384 + wid * 2048 + 1024),\
        16, 0, 0);                                                                   \
  }

  bf16x8 afA[4][2], afB[4][2], b0[2][2], b1[2][2];
  f32x4 acc[8][4];
#pragma unroll
  for (int i = 0; i < 8; ++i)
#pragma unroll
    for (int j = 0; j < 4; ++j) acc[i][j] = (f32x4)0.0f;

#define RD_A(bufl, mq, dst)                                                          \
  _Pragma("unroll") for (int ii = 0; ii < 4; ++ii) {                                 \
    dst[ii][0] = *(const bf16x8*)(smem + baseA0 +                                    \
                                  ((bufl) * 32768 + (mq) * 8192 + ii * 2048));       \
    dst[ii][1] = *(const bf16x8*)(smem + baseA1 +                                    \
                                  ((bufl) * 32768 + (mq) * 8192 + ii * 2048));       \
  }
#define RD_B(bufl, q, arr)                                                           \
  _Pragma("unroll") for (int jj = 0; jj < 2; ++jj) {                                 \
    arr[jj][0] = *(const bf16x8*)(smem + baseB0 +                                    \
                                  ((bufl) * 32768 + (q) * 4096 + jj * 2048));        \
    arr[jj][1] = *(const bf16x8*)(smem + baseB1 +                                    \
                                  ((bufl) * 32768 + (q) * 4096 + jj * 2048));        \
  }
#define MFMA_Q(mq, q, A, arr)                                                        \
  _Pragma("unroll") for (int kk = 0; kk < 2; ++kk)                                   \
  _Pragma("unroll") for (int ii = 0; ii < 4; ++ii)                                   \
  _Pragma("unroll") for (int jj = 0; jj < 2; ++jj)                                   \
      acc[(mq)*4+ii][(q)*2+jj] = __builtin_amdgcn_mfma_f32_16x16x32_bf16(            \
          A[ii][kk], arr[jj][kk], acc[(mq)*4+ii][(q)*2+jj], 0, 0, 0);

#define BAR __builtin_amdgcn_s_barrier()
#define PRIO1 __builtin_amdgcn_s_setprio(1)
#define PRIO0 __builtin_amdgcn_s_setprio(0)
#define LGK0                                               \
  {                                                        \
    asm volatile("s_waitcnt lgkmcnt(0)" ::: "memory");     \
    __builtin_amdgcn_sched_barrier(0);                     \
  }
#define VM4 asm volatile("s_waitcnt vmcnt(4)" ::: "memory")
#define VM8 asm volatile("s_waitcnt vmcnt(8)" ::: "memory")

  // Reads-early subtile: phase = [wait; MFMA; next-phase ops; BAR]
#define SUBTILE(bufl, SC)                                                            \
  /* p0 */                                                                           \
  LGK0; PRIO1; MFMA_Q(0, 0, afA, b0) PRIO0;                                          \
  RD_B(bufl, 1, b1)                                                                  \
  BAR;                                                                               \
  /* p1 */                                                                           \
  LGK0; PRIO1; MFMA_Q(0, 1, afA, b1) PRIO0;                                          \
  RD_A(bufl, 1, afB)                                                                 \
  BAR;                                                                               \
  /* p2: B of bufl fully consumed (b1 done p1-LGK0) -> stage B(t+2) */               \
  LGK0; PRIO1; MFMA_Q(1, 0, afB, b0) PRIO0;                                          \
  ST_B(bufl, 0, SC) ST_B(bufl, 1, SC)                                                \
  VM4;                                                                               \
  BAR;                                                                               \
  /* p3: A of bufl consumed -> stage A(t+2); pre-read next tile's afA,b0 */          \
  PRIO1; MFMA_Q(1, 1, afB, b1) PRIO0;                                                \
  ST_A(bufl, 0, SC) ST_A(bufl, 1, SC)                                                \
  RD_A((bufl) ^ 1, 0, afA)                                                           \
  RD_B((bufl) ^ 1, 0, b0)                                                            \
  BAR;

  const int NT = K >> 6;

  // prologue: stage tile0->buf0, tile1->buf1; drain tile0; pre-read afA,b0
  ST_A(0, 0, 0) ST_A(0, 1, 0) ST_B(0, 0, 0) ST_B(0, 1, 0)
  ST_A(1, 0, 64) ST_A(1, 1, 64) ST_B(1, 0, 64) ST_B(1, 1, 64)
  VM8;
  BAR;
  RD_A(0, 0, afA)
  RD_B(0, 0, b0)
#pragma unroll
  for (int j = 0; j < 2; ++j) { pSA0[j] += 128; pSA1[j] += 128; pSB0[j] += 128; pSB1[j] += 128; }

  for (int t = 0; t < NT; t += 2) {
    SUBTILE(0, 0)
    SUBTILE(1, 64)
    if (t + 4 < NT) {
#pragma unroll
      for (int j = 0; j < 2; ++j) { pSA0[j] += 128; pSA1[j] += 128; pSB0[j] += 128; pSB1[j] += 128; }
    }
  }

  // epilogue: C/D layout col=lane&15, row=(lane>>4)*4+j
#pragma unroll
  for (int nf = 0; nf < 4; ++nf) {
    const int col = n0 + wc * 64 + nf * 16 + l15;
    const float bv = bias[col];
#pragma unroll
    for (int mi = 0; mi < 8; ++mi) {
      const int row = m0 + wr * 128 + mi * 16 + l16 * 4;
#pragma unroll
      for (int j = 0; j < 4; ++j)
        out[(size_t)(row + j) * N + col] = acc[mi][nf][j] + bv;
    }
  }
#undef ST_A
#undef ST_B
#undef RD_A
#undef RD_B
#undef MFMA_Q
#undef BAR
#undef PRIO1
#undef PRIO0
#undef LGK0
#undef VM4
#undef VM8
#undef SUBTILE
}

extern "C" void kernel_launch(void* const* d_in, const int* in_sizes, int n_in,
                              void* d_out, int out_size, void* d_ws, size_t ws_size,
                              hipStream_t stream) {
  const float* x = (const float*)d_in[0];
  const int* qw = (const int*)d_in[1];
  const float* qs = (const float*)d_in[2];
  const float* bias = (const float*)d_in[3];
  const float* lA = (const float*)d_in[4];
  const float* lB = (const float*)d_in[5];
  float* out = (float*)d_out;

  const int OUT = in_sizes[3];
  const long qn = (long)in_sizes[1];
  const int IN = (int)(qn / OUT);
  const int R = in_sizes[5] / OUT;
  const long xn = (long)in_sizes[0];
  const int M = (int)(xn / IN);
  const int N = OUT, K = IN;

  unsigned short* Wb = (unsigned short*)d_ws;   // OUT*IN bf16
  unsigned short* Xb = Wb + qn;                 // M*IN bf16

  const int shIN = 31 - __builtin_clz((unsigned)IN);

  const long w8 = qn / 8;
  const long x8 = xn / 8;
  const long nchunks = w8 + x8;
  k_prep<<<(int)((nchunks + 255) / 256), 256, 0, stream>>>(
      qw, qs, lA, lB, x, Wb, Xb, IN, shIN, R, w8, x8);

  dim3 grid((M / 256) * (N / 256));
  k_gemm_256<<<grid, 512, 0, stream>>>(Xb, Wb, bias, out, M, N, K);
}

// Round 13
// 202.581 us; speedup vs baseline: 1.8431x; 1.4444x over previous
//
#include <hip/hip_runtime.h>
#include <hip/hip_bf16.h>
#include <stdint.h>

typedef int i32x4 __attribute__((ext_vector_type(4)));

#define AS1 __attribute__((address_space(1)))
#define AS3 __attribute__((address_space(3)))

__constant__ float c_nf4[16] = {
    -1.0f, -0.6961928009986877f, -0.5250730514526367f, -0.39491748809814453f,
    -0.28444138169288635f, -0.18477343022823334f, -0.09105003625154495f, 0.0f,
    0.07958029955625534f, 0.16093020141124725f, 0.24611230194568634f,
    0.33791524171829224f, 0.44070982933044434f, 0.5626170039176941f,
    0.7229568362236023f, 1.0f};

// ---------------------------------------------------------------------------
// Fused row-quantize prep. Block row r in [0,OUT): W_eff row -> int8 + sw.
// Block row in [OUT, OUT+M): X row -> int8 + sx. 256 thr, 16 elems/thread.
// W_eff = nf4[q]*group_scale + 4.0 * sum_r B[o][r]*A[r][i]; per-row absmax
// -> scale = am/127; q = rint(v*127/am). Exact per-row factorization.
// ---------------------------------------------------------------------------
__global__ __launch_bounds__(256) void k_prepq(
    const int* __restrict__ q, const float* __restrict__ scale,
    const float* __restrict__ lA, const float* __restrict__ lB,
    const float* __restrict__ x, int8_t* __restrict__ Wq,
    int8_t* __restrict__ Xq, float* __restrict__ sw, float* __restrict__ sx,
    int IN, int R, int OUT) {
  const int row = blockIdx.x;
  const int t = threadIdx.x;
  const int i0 = t * 16;
  float v[16];

  if (row < OUT) {
    const long e0 = (long)row * IN + i0;
    const float s = scale[e0 >> 6];  // 16 elems lie within one 64-group
    const int* qp = q + e0;
#pragma unroll
    for (int c = 0; c < 4; ++c) {
      int4 qa = *(const int4*)(qp + c * 4);
      v[c * 4 + 0] = c_nf4[qa.x & 15] * s;
      v[c * 4 + 1] = c_nf4[qa.y & 15] * s;
      v[c * 4 + 2] = c_nf4[qa.z & 15] * s;
      v[c * 4 + 3] = c_nf4[qa.w & 15] * s;
    }
    for (int r = 0; r < R; ++r) {
      const float br = 4.0f * lB[row * R + r];
      const float* ap = lA + (long)r * IN + i0;
#pragma unroll
      for (int c = 0; c < 4; ++c) {
        float4 a = *(const float4*)(ap + c * 4);
        v[c * 4 + 0] += br * a.x; v[c * 4 + 1] += br * a.y;
        v[c * 4 + 2] += br * a.z; v[c * 4 + 3] += br * a.w;
      }
    }
  } else {
    const int xr = row - OUT;
    const float* xp = x + (long)xr * IN + i0;
#pragma unroll
    for (int c = 0; c < 4; ++c) {
      float4 a = *(const float4*)(xp + c * 4);
      v[c * 4 + 0] = a.x; v[c * 4 + 1] = a.y;
      v[c * 4 + 2] = a.z; v[c * 4 + 3] = a.w;
    }
  }

  float am = 0.0f;
#pragma unroll
  for (int i = 0; i < 16; ++i) am = fmaxf(am, fabsf(v[i]));
#pragma unroll
  for (int m = 32; m >= 1; m >>= 1) am = fmaxf(am, __shfl_xor(am, m));
  __shared__ float red[4];
  if ((t & 63) == 0) red[t >> 6] = am;
  __syncthreads();
  am = fmaxf(fmaxf(red[0], red[1]), fmaxf(red[2], red[3]));
  am = fmaxf(am, 1e-30f);
  const float inv = 127.0f / am;

  union { int8_t c[16]; int4 p; } pk;
#pragma unroll
  for (int i = 0; i < 16; ++i) pk.c[i] = (int8_t)(int)rintf(v[i] * inv);

  if (row < OUT) {
    *(int4*)(Wq + (long)row * IN + i0) = pk.p;
    if (t == 0) sw[row] = am * (1.0f / 127.0f);
  } else {
    const int xr = row - OUT;
    *(int4*)(Xq + (long)xr * IN + i0) = pk.p;
    if (t == 0) sx[xr] = am * (1.0f / 127.0f);
  }
}

// ---------------------------------------------------------------------------
// 256x256 tile, BK=128 (i8), 8 waves (2M x 4N), 4 phases/tile — byte-
// isomorphic to the verified R6 bf16 schedule (same 128-B rows, same XOR
// swizzle -> conflict-free, same reads-early phase structure), but MFMA =
// mfma_i32_16x16x64_i8 (2x rate), NT = K/128 (half the tiles), exact int32
// accumulation. Epilogue: out = sx[row]*sw[col]*acc + bias[col].
// ---------------------------------------------------------------------------
__global__ __launch_bounds__(512, 2) void k_gemm_256(
    const int8_t* __restrict__ Xq, const int8_t* __restrict__ Wq,
    const float* __restrict__ sx, const float* __restrict__ sw,
    const float* __restrict__ bias, float* __restrict__ out,
    int M, int N, int K) {
  __shared__ char smem[131072];
  const int tid = threadIdx.x;
  const int wid = tid >> 6;
  const int lane = tid & 63;
  const int wr = wid >> 2;
  const int wc = wid & 3;
  const int wcl = wc & 1;
  const int l15 = lane & 15;
  const int l16 = lane >> 4;

  // reader swizzle decomposition: (kk*64 + l16*16) ^ ((l15&7)<<4)  [bytes]
  const int kflip = (l15 & 4) ? 64 : 0;
  const int lowx = ((l16 ^ (l15 & 3)) << 4);
  const int baseA0 = wr * 16384 + l15 * 128 + lowx + kflip;
  const int baseA1 = wr * 16384 + l15 * 128 + lowx + (64 ^ kflip);
  const int baseB0 = 65536 + (wc >> 1) * 16384 + wcl * 8192 + l15 * 128 + lowx + kflip;
  const int baseB1 = baseB0 + (64 ^ kflip) - kflip;

  int bid = blockIdx.x;
  const int nwg = gridDim.x;
  if ((nwg & 7) == 0) { const int cpx = nwg >> 3; bid = (bid & 7) * cpx + (bid >> 3); }
  const int nbn = N >> 8;
  const int m0 = (bid / nbn) << 8;
  const int n0 = (bid % nbn) << 8;

  // per-lane pre-swizzled global byte offsets for staging
  int rowj[2], gcj[2];
#pragma unroll
  for (int j = 0; j < 2; ++j) {
    const int lo = wid * 2048 + j * 1024 + lane * 16;
    const int row = lo >> 7;
    const int ls = lo ^ ((row & 7) << 4);
    rowj[j] = row;
    gcj[j] = ls & 127;  // byte col within 128-B K-tile row
  }
  const size_t halfstep = (size_t)128 * K;
  const int8_t* pSA0[2]; const int8_t* pSA1[2];
  const int8_t* pSB0[2]; const int8_t* pSB1[2];
#pragma unroll
  for (int j = 0; j < 2; ++j) {
    pSA0[j] = Xq + (size_t)(m0 + rowj[j]) * K + gcj[j];
    pSA1[j] = pSA0[j] + halfstep;
    pSB0[j] = Wq + (size_t)(n0 + rowj[j]) * K + gcj[j];
    pSB1[j] = pSB0[j] + halfstep;
  }

#define ST_A(bufl, h, coff)                                                          \
  {                                                                                  \
    __builtin_amdgcn_global_load_lds((const AS1 void*)(pSA##h[0] + (coff)),          \
        (AS3 void*)(smem + (bufl) * 32768 + (h) * 16384 + wid * 2048), 16, 0, 0);    \
    __builtin_amdgcn_global_load_lds((const AS1 void*)(pSA##h[1] + (coff)),          \
        (AS3 void*)(smem + (bufl) * 32768 + (h) * 16384 + wid * 2048 + 1024),        \
        16, 0, 0);                                                                   \
  }
#define ST_B(bufl, h, coff)                                                          \
  {                                                                                  \
    __builtin_amdgcn_global_load_lds((const AS1 void*)(pSB##h[0] + (coff)),          \
        (AS3 void*)(smem + 65536 + (bufl) * 32768 + (h) * 16384 + wid * 2048),       \
        16, 0, 0);                                                                   \
    __builtin_amdgcn_global_load_lds((const AS1 void*)(pSB##h[1] + (coff)),          \
        (AS3 void*)(smem + 65536 + (bufl) * 32768 + (h) * 16384 + wid * 2048 + 1024),\
        16, 0, 0);                                                                   \
  }

  i32x4 afA[4][2], afB[4][2], b0[2][2], b1[2][2];
  i32x4 acc[8][4];
#pragma unroll
  for (int i = 0; i < 8; ++i)
#pragma unroll
    for (int j = 0; j < 4; ++j) acc[i][j] = (i32x4)0;

#define RD_A(bufl, mq, dst)                                                          \
  _Pragma("unroll") for (int ii = 0; ii < 4; ++ii) {                                 \
    dst[ii][0] = *(const i32x4*)(smem + baseA0 +                                     \
                                 ((bufl) * 32768 + (mq) * 8192 + ii * 2048));        \
    dst[ii][1] = *(const i32x4*)(smem + baseA1 +                                     \
                                 ((bufl) * 32768 + (mq) * 8192 + ii * 2048));        \
  }
#define RD_B(bufl, q, arr)                                                           \
  _Pragma("unroll") for (int jj = 0; jj < 2; ++jj) {                                 \
    arr[jj][0] = *(const i32x4*)(smem + baseB0 +                                     \
                                 ((bufl) * 32768 + (q) * 4096 + jj * 2048));         \
    arr[jj][1] = *(const i32x4*)(smem + baseB1 +                                     \
                                 ((bufl) * 32768 + (q) * 4096 + jj * 2048));         \
  }
#define MFMA_Q(mq, q, A, arr)                                                        \
  _Pragma("unroll") for (int kk = 0; kk < 2; ++kk)                                   \
  _Pragma("unroll") for (int ii = 0; ii < 4; ++ii)                                   \
  _Pragma("unroll") for (int jj = 0; jj < 2; ++jj)                                   \
      acc[(mq)*4+ii][(q)*2+jj] = __builtin_amdgcn_mfma_i32_16x16x64_i8(              \
          A[ii][kk], arr[jj][kk], acc[(mq)*4+ii][(q)*2+jj], 0, 0, 0);

#define BAR __builtin_amdgcn_s_barrier()
#define PRIO1 __builtin_amdgcn_s_setprio(1)
#define PRIO0 __builtin_amdgcn_s_setprio(0)
#define LGK0                                               \
  {                                                        \
    asm volatile("s_waitcnt lgkmcnt(0)" ::: "memory");     \
    __builtin_amdgcn_sched_barrier(0);                     \
  }
#define VM4 asm volatile("s_waitcnt vmcnt(4)" ::: "memory")
#define VM8 asm volatile("s_waitcnt vmcnt(8)" ::: "memory")

  // Reads-early subtile (R6 schedule, verified): [wait; MFMA; next ops; BAR]
#define SUBTILE(bufl, SC)                                                            \
  /* p0 */                                                                           \
  LGK0; PRIO1; MFMA_Q(0, 0, afA, b0) PRIO0;                                          \
  RD_B(bufl, 1, b1)                                                                  \
  BAR;                                                                               \
  /* p1 */                                                                           \
  LGK0; PRIO1; MFMA_Q(0, 1, afA, b1) PRIO0;                                          \
  RD_A(bufl, 1, afB)                                                                 \
  BAR;                                                                               \
  /* p2: B of bufl fully consumed -> stage B(t+2) */                                 \
  LGK0; PRIO1; MFMA_Q(1, 0, afB, b0) PRIO0;                                          \
  ST_B(bufl, 0, SC) ST_B(bufl, 1, SC)                                                \
  VM4;                                                                               \
  BAR;                                                                               \
  /* p3: A of bufl consumed -> stage A(t+2); pre-read next tile's afA,b0 */          \
  PRIO1; MFMA_Q(1, 1, afB, b1) PRIO0;                                                \
  ST_A(bufl, 0, SC) ST_A(bufl, 1, SC)                                                \
  RD_A((bufl) ^ 1, 0, afA)                                                           \
  RD_B((bufl) ^ 1, 0, b0)                                                            \
  BAR;

  const int NT = K >> 7;   // BK = 128 i8

  // prologue: stage tile0->buf0, tile1->buf1; drain tile0; pre-read afA,b0
  ST_A(0, 0, 0) ST_A(0, 1, 0) ST_B(0, 0, 0) ST_B(0, 1, 0)
  ST_A(1, 0, 128) ST_A(1, 1, 128) ST_B(1, 0, 128) ST_B(1, 1, 128)
  VM8;
  BAR;
  RD_A(0, 0, afA)
  RD_B(0, 0, b0)
#pragma unroll
  for (int j = 0; j < 2; ++j) { pSA0[j] += 256; pSA1[j] += 256; pSB0[j] += 256; pSB1[j] += 256; }

  for (int t = 0; t < NT; t += 2) {
    SUBTILE(0, 0)
    SUBTILE(1, 128)
    if (t + 4 < NT) {
#pragma unroll
      for (int j = 0; j < 2; ++j) { pSA0[j] += 256; pSA1[j] += 256; pSB0[j] += 256; pSB1[j] += 256; }
    }
  }

  // epilogue: C/D col=lane&15, row=(lane>>4)*4+j; out = sx*sw*acc + bias
  float bv[4], swc[4];
#pragma unroll
  for (int nf = 0; nf < 4; ++nf) {
    const int col = n0 + wc * 64 + nf * 16 + l15;
    bv[nf] = bias[col];
    swc[nf] = sw[col];
  }
#pragma unroll
  for (int mi = 0; mi < 8; ++mi) {
    const int rbase = m0 + wr * 128 + mi * 16 + l16 * 4;
    const float4 sx4 = *(const float4*)(sx + rbase);
#pragma unroll
    for (int nf = 0; nf < 4; ++nf) {
      const int col = n0 + wc * 64 + nf * 16 + l15;
      const float s0 = sx4.x * swc[nf], s1 = sx4.y * swc[nf];
      const float s2 = sx4.z * swc[nf], s3 = sx4.w * swc[nf];
      out[(size_t)(rbase + 0) * N + col] = (float)acc[mi][nf][0] * s0 + bv[nf];
      out[(size_t)(rbase + 1) * N + col] = (float)acc[mi][nf][1] * s1 + bv[nf];
      out[(size_t)(rbase + 2) * N + col] = (float)acc[mi][nf][2] * s2 + bv[nf];
      out[(size_t)(rbase + 3) * N + col] = (float)acc[mi][nf][3] * s3 + bv[nf];
    }
  }
#undef ST_A
#undef ST_B
#undef RD_A
#undef RD_B
#undef MFMA_Q
#undef BAR
#undef PRIO1
#undef PRIO0
#undef LGK0
#undef VM4
#undef VM8
#undef SUBTILE
}

extern "C" void kernel_launch(void* const* d_in, const int* in_sizes, int n_in,
                              void* d_out, int out_size, void* d_ws, size_t ws_size,
                              hipStream_t stream) {
  const float* x = (const float*)d_in[0];
  const int* qw = (const int*)d_in[1];
  const float* qs = (const float*)d_in[2];
  const float* bias = (const float*)d_in[3];
  const float* lA = (const float*)d_in[4];
  const float* lB = (const float*)d_in[5];
  float* out = (float*)d_out;

  const int OUT = in_sizes[3];
  const long qn = (long)in_sizes[1];
  const int IN = (int)(qn / OUT);
  const int R = in_sizes[5] / OUT;
  const long xn = (long)in_sizes[0];
  const int M = (int)(xn / IN);
  const int N = OUT, K = IN;

  // workspace: Wq[qn] i8 | Xq[xn] i8 | sw[OUT] f32 | sx[M] f32 (16B aligned)
  int8_t* Wq = (int8_t*)d_ws;
  int8_t* Xq = Wq + qn;
  float* sw = (float*)(((uintptr_t)(Xq + xn) + 15) & ~(uintptr_t)15);
  float* sx = sw + OUT;

  k_prepq<<<OUT + M, 256, 0, stream>>>(qw, qs, lA, lB, x, Wq, Xq, sw, sx, IN, R, OUT);

  dim3 grid((M / 256) * (N / 256));
  k_gemm_256<<<grid, 512, 0, stream>>>(Xq, Wq, sx, sw, bias, out, M, N, K);
}